// Round 10
// baseline (147.638 us; speedup 1.0000x reference)
//
#include <hip/hip_runtime.h>
#include <math.h>

// Problem constants
#define BB   1024
#define MM   32
#define NN   64
#define DD   32
#define NOBJ 20
#define NV   6890
#define KK   6144      // M*N*3
#define JJ   192       // N*3

// ---------------------------------------------------------------------------
// Kernel 1: reduce pca_components / pca_means over m (sum of M=32 strided
// rows), float4-vectorized. Cred[od*192 + j] = sum_m comps[od][m*192 + j]
// ---------------------------------------------------------------------------
__global__ void reduce_pca(const float* __restrict__ comps,
                           const float* __restrict__ means,
                           float* __restrict__ Cred,
                           float* __restrict__ Mred) {
    int t = blockIdx.x * blockDim.x + threadIdx.x;
    const int NC4 = NOBJ * DD * 48;          // 30720 float4 chunks for Cred
    if (t < NC4) {
        int jv = t % 48;
        int od = t / 48;                     // o*D + d
        const float4* p = reinterpret_cast<const float4*>(
            comps + (size_t)od * KK + jv * 4);
        float4 s = make_float4(0.f, 0.f, 0.f, 0.f);
#pragma unroll
        for (int m = 0; m < MM; ++m) {
            float4 v = p[m * 48];            // stride 192 floats
            s.x += v.x; s.y += v.y; s.z += v.z; s.w += v.w;
        }
        reinterpret_cast<float4*>(Cred)[t] = s;
    } else {
        int t2 = t - NC4;
        if (t2 < NOBJ * 48) {
            int jv = t2 % 48;
            int o  = t2 / 48;
            const float4* p = reinterpret_cast<const float4*>(
                means + (size_t)o * KK + jv * 4);
            float4 s = make_float4(0.f, 0.f, 0.f, 0.f);
#pragma unroll
            for (int m = 0; m < MM; ++m) {
                float4 v = p[m * 48];
                s.x += v.x; s.y += v.y; s.z += v.z; s.w += v.w;
            }
            reinterpret_cast<float4*>(Mred)[t2] = s;
        }
    }
}

// ---------------------------------------------------------------------------
// Kernel 2 (fused, ONE WAVE per batch): OffSum mat-vec -> cross-moment
// butterfly ALL-reduce (every lane ends with the full H, c, meanP) ->
// all 64 lanes redundantly run the f32 branchless Jacobi in lockstep
// (no divergence, no LDS/global round-trip, ~45 VGPRs -> no spill) ->
// lane 0 writes R and T. Eliminates the separate `solve` launch, its
// dependency edge, and the Hc buffer.
// ---------------------------------------------------------------------------
__global__ __launch_bounds__(64) void per_batch(
    const float* __restrict__ gamma,    // [B,32]
    const float* __restrict__ smpl_v,   // [B,NV,3]
    const float* __restrict__ oanch,    // [NOBJ,64,3]
    const int*   __restrict__ labels,   // [B]
    const int*   __restrict__ sidx,     // [32]
    const float* __restrict__ Cred,     // [NOBJ, D, 192]
    const float* __restrict__ Mred,     // [NOBJ, 192]
    float* __restrict__ out)            // R flat [B*9] then T flat [B*3]
{
    const int b    = blockIdx.x;
    const int lane = threadIdx.x;       // 0..63
    const int o    = labels[b];         // wave-uniform

    const int j0 = lane, j1 = lane + 64, j2 = lane + 128;

    // OffSum[j] = Mred[o][j] + sum_d Cred[o][d][j] * gamma[d]
    const float* Co = Cred + (size_t)o * DD * JJ;
    const float* Mo = Mred + (size_t)o * JJ;
    float off0 = Mo[j0], off1 = Mo[j1], off2 = Mo[j2];
#pragma unroll
    for (int d = 0; d < DD; ++d) {
        float g = gamma[b * DD + d];    // uniform address -> s_load
        off0 += Co[d * JJ + j0] * g;
        off1 += Co[d * JJ + j1] * g;
        off2 += Co[d * JJ + j2] * g;
    }

    const float* Oo = oanch + (size_t)o * JJ;
    float oa0 = Oo[j0], oa1 = Oo[j1], oa2 = Oo[j2];

    // SMPL anchor gather + sum over m (lanes 0..31 contribute)
    float sax = 0.f, say = 0.f, saz = 0.f;
    if (lane < MM) {
        int v = sidx[lane];
        const float* p = smpl_v + ((size_t)b * NV + v) * 3;
        sax = p[0]; say = p[1]; saz = p[2];
    }

    // Stage off/oa to LDS so lane n can grab anchor n's (x,y,z).
    __shared__ float s_off[JJ];
    __shared__ float s_oa[JJ];
    s_off[j0] = off0; s_off[j1] = off1; s_off[j2] = off2;
    s_oa[j0]  = oa0;  s_oa[j1]  = oa1;  s_oa[j2]  = oa2;
    __syncthreads();                    // single-wave block: just a waitcnt

    const int n = lane;                 // anchor index, 0..63
    float p0 = s_off[n * 3 + 0], p1 = s_off[n * 3 + 1], p2 = s_off[n * 3 + 2];
    float q0 = s_oa[n * 3 + 0],  q1 = s_oa[n * 3 + 1],  q2 = s_oa[n * 3 + 2];

    // Butterfly ALL-reduce of 18 values: Hraw(9), sumoff(3), sumoa(3), SA(3)
    float r0  = p0 * q0, r1  = p0 * q1, r2  = p0 * q2;
    float r3  = p1 * q0, r4  = p1 * q1, r5  = p1 * q2;
    float r6  = p2 * q0, r7  = p2 * q1, r8  = p2 * q2;

#pragma unroll
    for (int s = 1; s < 64; s <<= 1) {
        r0 += __shfl_xor(r0, s); r1 += __shfl_xor(r1, s); r2 += __shfl_xor(r2, s);
        r3 += __shfl_xor(r3, s); r4 += __shfl_xor(r4, s); r5 += __shfl_xor(r5, s);
        r6 += __shfl_xor(r6, s); r7 += __shfl_xor(r7, s); r8 += __shfl_xor(r8, s);
        p0 += __shfl_xor(p0, s); p1 += __shfl_xor(p1, s); p2 += __shfl_xor(p2, s);
        q0 += __shfl_xor(q0, s); q1 += __shfl_xor(q1, s); q2 += __shfl_xor(q2, s);
        sax += __shfl_xor(sax, s); say += __shfl_xor(say, s); saz += __shfl_xor(saz, s);
    }

    // Every lane now holds the totals. Build H, c, meanP in registers.
    const float c0 = q0 * (1.f / NN), c1 = q1 * (1.f / NN), c2 = q2 * (1.f / NN);
    const float H00 = r0 - p0 * c0, H01 = r1 - p0 * c1, H02 = r2 - p0 * c2;
    const float H10 = r3 - p1 * c0, H11 = r4 - p1 * c1, H12 = r5 - p1 * c2;
    const float H20 = r6 - p2 * c0, H21 = r7 - p2 * c1, H22 = r8 - p2 * c2;
    const float mP0 = sax * (1.f / MM) + p0 * (1.f / (MM * NN));
    const float mP1 = say * (1.f / MM) + p1 * (1.f / (MM * NN));
    const float mP2 = saz * (1.f / MM) + p2 * (1.f / (MM * NN));

    // Horn 4x4 K-matrix; branchless cyclic Jacobi, all lanes in lockstep.
    float A[4][4], V[4][4];
    A[0][0] =  H00 + H11 + H22;
    A[1][1] =  H00 - H11 - H22;
    A[2][2] = -H00 + H11 - H22;
    A[3][3] = -H00 - H11 + H22;
    A[0][1] = A[1][0] = H21 - H12;
    A[0][2] = A[2][0] = H02 - H20;
    A[0][3] = A[3][0] = H10 - H01;
    A[1][2] = A[2][1] = H01 + H10;
    A[1][3] = A[3][1] = H02 + H20;
    A[2][3] = A[3][2] = H12 + H21;
#pragma unroll
    for (int r = 0; r < 4; ++r)
#pragma unroll
        for (int cc2 = 0; cc2 < 4; ++cc2) V[r][cc2] = (r == cc2) ? 1.f : 0.f;

    for (int sweep = 0; sweep < 8; ++sweep) {
#pragma unroll
        for (int p = 0; p < 3; ++p) {
#pragma unroll
            for (int q = p + 1; q < 4; ++q) {
                float apq  = A[p][q];
                float diff = A[q][q] - A[p][p];
                float sd   = (diff >= 0.f) ? 1.f : -1.f;
                float tt = 2.f * apq * sd /
                           (fabsf(diff) + sqrtf(diff * diff + 4.f * apq * apq)
                            + 1e-30f);
                float cc = 1.f / sqrtf(1.f + tt * tt);
                float ss = tt * cc;
#pragma unroll
                for (int k = 0; k < 4; ++k) {
                    float akp = A[k][p], akq = A[k][q];
                    A[k][p] = cc * akp - ss * akq;
                    A[k][q] = ss * akp + cc * akq;
                }
#pragma unroll
                for (int k = 0; k < 4; ++k) {
                    float apk = A[p][k], aqk = A[q][k];
                    A[p][k] = cc * apk - ss * aqk;
                    A[q][k] = ss * apk + cc * aqk;
                }
#pragma unroll
                for (int k = 0; k < 4; ++k) {
                    float vkp = V[k][p], vkq = V[k][q];
                    V[k][p] = cc * vkp - ss * vkq;
                    V[k][q] = ss * vkp + cc * vkq;
                }
            }
        }
    }

    float best = A[0][0];
    float w = V[0][0], x = V[1][0], y = V[2][0], z = V[3][0];
#pragma unroll
    for (int i = 1; i < 4; ++i) {
        bool gt = A[i][i] > best;
        best = gt ? A[i][i] : best;
        w = gt ? V[0][i] : w;
        x = gt ? V[1][i] : x;
        y = gt ? V[2][i] : y;
        z = gt ? V[3][i] : z;
    }
    float inv = 1.f / sqrtf(w * w + x * x + y * y + z * z);
    w *= inv; x *= inv; y *= inv; z *= inv;

    float R00 = w * w + x * x - y * y - z * z;
    float R01 = 2.f * (x * y - w * z);
    float R02 = 2.f * (x * z + w * y);
    float R10 = 2.f * (x * y + w * z);
    float R11 = w * w - x * x + y * y - z * z;
    float R12 = 2.f * (y * z - w * x);
    float R20 = 2.f * (x * z - w * y);
    float R21 = 2.f * (y * z + w * x);
    float R22 = w * w - x * x - y * y + z * z;

    if (lane == 0) {
        float* Rout = out + (size_t)b * 9;
        Rout[0] = R00; Rout[1] = R01; Rout[2] = R02;
        Rout[3] = R10; Rout[4] = R11; Rout[5] = R12;
        Rout[6] = R20; Rout[7] = R21; Rout[8] = R22;

        float* Tout = out + (size_t)BB * 9 + (size_t)b * 3;
        Tout[0] = mP0 - (R00 * c0 + R01 * c1 + R02 * c2);
        Tout[1] = mP1 - (R10 * c0 + R11 * c1 + R12 * c2);
        Tout[2] = mP2 - (R20 * c0 + R21 * c1 + R22 * c2);
    }
}

extern "C" void kernel_launch(void* const* d_in, const int* in_sizes, int n_in,
                              void* d_out, int out_size, void* d_ws, size_t ws_size,
                              hipStream_t stream) {
    const float* gamma  = (const float*)d_in[0];
    const float* smpl_v = (const float*)d_in[1];
    const float* comps  = (const float*)d_in[2];
    const float* means  = (const float*)d_in[3];
    const float* oanch  = (const float*)d_in[4];
    const int*   labels = (const int*)d_in[5];
    const int*   sidx   = (const int*)d_in[6];
    float* out = (float*)d_out;

    float* Cred = (float*)d_ws;                       // 122880 floats
    float* Mred = Cred + NOBJ * DD * JJ;              // 3840 floats

    const int total4 = NOBJ * DD * 48 + NOBJ * 48;    // 31680 float4 tasks
    reduce_pca<<<(total4 + 255) / 256, 256, 0, stream>>>(comps, means, Cred, Mred);
    per_batch<<<BB, 64, 0, stream>>>(gamma, smpl_v, oanch, labels, sidx,
                                     Cred, Mred, out);
}